// Round 1
// baseline (3053.585 us; speedup 1.0000x reference)
//
#include <hip/hip_runtime.h>
#include <hip/hip_bf16.h>

// ---------------------------------------------------------------------------
// 2-layer GRU, B=64 S=2048 IN=208 H=100 OUT=98, fp32 throughout.
// Pipeline per chunk of S:
//   1) gemm_bias: xg0 = seq @ w_ih_l0^T + b_ih_l0
//   2) gru_scan : layer-0 recurrence (64 persistent blocks, 1 per batch)
//   3) gemm_bias: xg1 = y0 @ w_ih_l1^T + b_ih_l1
//   4) gru_scan : layer-1 recurrence
//   5) gemm_bias: out = y1 @ w_out^T + b_out
// ---------------------------------------------------------------------------

#define GB_BM 64
#define GB_BN 64
#define GB_BK 16

__global__ __launch_bounds__(256)
void gemm_bias(const float* __restrict__ A, const float* __restrict__ W,
               const float* __restrict__ bias, float* __restrict__ C,
               int Sc, long a_bs, long a_ss, long c_bs, long c_ss,
               int N, int K)
{
    // C[row, n] = sum_k A[row, k] * W[n, k] + bias[n]
    // row -> (b = row / Sc, sc = row % Sc); A addr = A + b*a_bs + sc*a_ss
    __shared__ float As[GB_BK][68];   // stride 68 keeps float4 reads 16B-aligned, 2-way banks only
    __shared__ float Bs[GB_BK][68];
    const int tid = threadIdx.x;
    const int m0 = blockIdx.x * GB_BM;
    const int n0 = blockIdx.y * GB_BN;

    const int lm = tid >> 2;          // 0..63
    const int lk = (tid & 3) << 2;    // 0,4,8,12
    const int row = m0 + lm;
    const float* arow = A + (long)(row / Sc) * a_bs + (long)(row % Sc) * a_ss;
    const int wrow = n0 + lm;
    const float* wrp = W + (long)wrow * K;
    const bool wv_ok = (wrow < N);

    const int tx = tid & 15;
    const int ty = tid >> 4;

    float acc[4][4] = {};

    for (int k0 = 0; k0 < K; k0 += GB_BK) {
        float4 av, bv;
        if (k0 + GB_BK <= K) {
            av = *(const float4*)(arow + k0 + lk);
            bv = wv_ok ? *(const float4*)(wrp + k0 + lk) : make_float4(0.f,0.f,0.f,0.f);
        } else {
            av = make_float4(0.f,0.f,0.f,0.f);
            bv = make_float4(0.f,0.f,0.f,0.f);
            const int kb = k0 + lk;
            if (kb + 0 < K) { av.x = arow[kb+0]; if (wv_ok) bv.x = wrp[kb+0]; }
            if (kb + 1 < K) { av.y = arow[kb+1]; if (wv_ok) bv.y = wrp[kb+1]; }
            if (kb + 2 < K) { av.z = arow[kb+2]; if (wv_ok) bv.z = wrp[kb+2]; }
            if (kb + 3 < K) { av.w = arow[kb+3]; if (wv_ok) bv.w = wrp[kb+3]; }
        }
        As[lk+0][lm] = av.x; As[lk+1][lm] = av.y; As[lk+2][lm] = av.z; As[lk+3][lm] = av.w;
        Bs[lk+0][lm] = bv.x; Bs[lk+1][lm] = bv.y; Bs[lk+2][lm] = bv.z; Bs[lk+3][lm] = bv.w;
        __syncthreads();
        #pragma unroll
        for (int kk = 0; kk < GB_BK; kk++) {
            float4 a  = *(const float4*)&As[kk][ty << 2];
            float4 bb = *(const float4*)&Bs[kk][tx << 2];
            float ar[4] = {a.x, a.y, a.z, a.w};
            float br[4] = {bb.x, bb.y, bb.z, bb.w};
            #pragma unroll
            for (int i = 0; i < 4; i++)
                #pragma unroll
                for (int j = 0; j < 4; j++)
                    acc[i][j] += ar[i] * br[j];
        }
        __syncthreads();
    }

    #pragma unroll
    for (int i = 0; i < 4; i++) {
        const int r = m0 + (ty << 2) + i;       // always < M (M % 64 == 0)
        float* crow = C + (long)(r / Sc) * c_bs + (long)(r % Sc) * c_ss;
        #pragma unroll
        for (int j = 0; j < 4; j++) {
            const int col = n0 + (tx << 2) + j;
            if (col < N) crow[col] = acc[i][j] + bias[col];
        }
    }
}

// ---------------------------------------------------------------------------
// Persistent GRU scan: grid = 64 blocks (one batch each), 640 threads.
// Threads 0..599: 2-way k-split dot products, w_hh rows in VGPRs (13 float4).
//   thread t: gate g = t>>1, k-half = t&1 (k 0..47 | 48..99, last f4 of half0 zeroed)
// Threads 0..99 additionally run the gate nonlinearity + h update.
// h lives in LDS (float4 broadcast reads: 2 distinct addrs/wave -> conflict-free).
// ---------------------------------------------------------------------------

__device__ __forceinline__ float fsig(float x)  { return 1.f / (1.f + __expf(-x)); }
__device__ __forceinline__ float ftanh(float x) { return 1.f - 2.f / (1.f + __expf(2.f * x)); }

__global__ __launch_bounds__(640, 1)
void gru_scan(const float* __restrict__ xg, const float* __restrict__ w_hh,
              const float* __restrict__ b_hh, const float* __restrict__ h_init,
              float* __restrict__ h_state, float* __restrict__ y,
              int Sc, int first)
{
    __shared__ __align__(16) float hs[100];
    __shared__ float hg_lds[300];
    __shared__ float xg_lds[300];

    const int tid = threadIdx.x;
    const int b = blockIdx.x;
    const int half = tid & 1;
    const int g = tid >> 1;
    const bool dot = (tid < 600);
    const bool even = dot && (half == 0);

    float4 wv[13];
    float bhh = 0.f;
    if (dot) {
        const float* wb = w_hh + g * 100 + half * 48;   // 16B aligned: (100g+48)%4==0
        #pragma unroll
        for (int i = 0; i < 13; i++) wv[i] = *(const float4*)(wb + 4 * i);
        if (!half) wv[12] = make_float4(0.f, 0.f, 0.f, 0.f);  // half0 covers k<48 only
    }
    if (even) bhh = b_hh[g];

    float hcur = 0.f;
    if (tid < 100) {
        hcur = first ? h_init[b * 100 + tid] : h_state[b * 100 + tid];
        hs[tid] = hcur;
    }

    const float* xgb = xg + (size_t)b * Sc * 300;
    float xnext = 0.f;
    if (even) xnext = xgb[g];          // prefetch t=0
    __syncthreads();

    for (int t = 0; t < Sc; t++) {
        const float xcur = xnext;
        if (even && (t + 1 < Sc)) xnext = xgb[(size_t)(t + 1) * 300 + g];  // prefetch t+1

        float tot = 0.f;
        if (dot) {
            const float4* hs4 = (const float4*)hs;
            const int base = half * 12;                 // half0: f 0..51, half1: f 48..99
            float a0 = 0.f, a1 = 0.f;
            #pragma unroll
            for (int i = 0; i < 13; i++) {
                const float4 h4 = hs4[base + i];
                const float4 w = wv[i];
                a0 += w.x * h4.x; a1 += w.y * h4.y;
                a0 += w.z * h4.z; a1 += w.w * h4.w;
            }
            tot = a0 + a1;
            tot += __shfl_down(tot, 1);                 // pair-sum: even lane gets full dot
        }
        if (even) { hg_lds[g] = tot + bhh; xg_lds[g] = xcur; }
        __syncthreads();

        if (tid < 100) {
            const float xr = xg_lds[tid], xz = xg_lds[100 + tid], xn = xg_lds[200 + tid];
            const float hr = hg_lds[tid], hz = hg_lds[100 + tid], hn = hg_lds[200 + tid];
            const float r = fsig(xr + hr);
            const float z = fsig(xz + hz);
            const float n = ftanh(xn + r * hn);
            hcur = (1.f - z) * n + z * hcur;
            hs[tid] = hcur;
            y[((size_t)b * Sc + t) * 100 + tid] = hcur;
        }
        __syncthreads();
    }

    if (tid < 100) h_state[b * 100 + tid] = hcur;
}

// ---------------------------------------------------------------------------

extern "C" void kernel_launch(void* const* d_in, const int* in_sizes, int n_in,
                              void* d_out, int out_size, void* d_ws, size_t ws_size,
                              hipStream_t stream)
{
    const float* seq    = (const float*)d_in[0];
    const float* h0     = (const float*)d_in[1];   // (2, 64, 100)
    const float* w_ih0  = (const float*)d_in[2];   // (300, 208)
    const float* w_hh0  = (const float*)d_in[3];   // (300, 100)
    const float* b_ih0  = (const float*)d_in[4];
    const float* b_hh0  = (const float*)d_in[5];
    const float* w_ih1  = (const float*)d_in[6];   // (300, 100)
    const float* w_hh1  = (const float*)d_in[7];
    const float* b_ih1  = (const float*)d_in[8];
    const float* b_hh1  = (const float*)d_in[9];
    const float* w_out  = (const float*)d_in[10];  // (98, 100)
    const float* b_out  = (const float*)d_in[11];
    float* out = (float*)d_out;

    const int B = 64, S = 2048, IN = 208, H = 100, G = 300, OUT = 98;

    // choose largest chunk Sc (power of 2 dividing S) whose buffers fit ws
    int Sc = S;
    while (Sc > 16) {
        size_t need = ((size_t)B * Sc * (G + H + H) + 2 * (size_t)B * H) * sizeof(float);
        if (need <= ws_size) break;
        Sc >>= 1;
    }
    const int NC = S / Sc;

    float* h0s = (float*)d_ws;                 // (B,H) persistent layer-0 state
    float* h1s = h0s + (size_t)B * H;          // (B,H) persistent layer-1 state
    float* y0c = h1s + (size_t)B * H;          // (B,Sc,H)
    float* y1c = y0c + (size_t)B * Sc * H;     // (B,Sc,H)
    float* xgc = y1c + (size_t)B * Sc * H;     // (B,Sc,3H)

    const dim3 blk(256);
    const dim3 gX((B * Sc) / GB_BM, (G + GB_BN - 1) / GB_BN);    // 300 -> 5
    const dim3 gO((B * Sc) / GB_BM, (OUT + GB_BN - 1) / GB_BN);  // 98  -> 2

    for (int c = 0; c < NC; c++) {
        const int s0 = c * Sc;
        const int first = (c == 0);

        // 1) xg0 = seq @ w_ih0^T + b_ih0
        gemm_bias<<<gX, blk, 0, stream>>>(seq + (long)s0 * IN, w_ih0, b_ih0, xgc,
                                          Sc, (long)S * IN, (long)IN,
                                          (long)Sc * G, (long)G, G, IN);
        // 2) layer-0 scan
        gru_scan<<<dim3(B), dim3(640), 0, stream>>>(xgc, w_hh0, b_hh0,
                                                    h0, h0s, y0c, Sc, first);
        // 3) xg1 = y0 @ w_ih1^T + b_ih1
        gemm_bias<<<gX, blk, 0, stream>>>(y0c, w_ih1, b_ih1, xgc,
                                          Sc, (long)Sc * H, (long)H,
                                          (long)Sc * G, (long)G, G, H);
        // 4) layer-1 scan
        gru_scan<<<dim3(B), dim3(640), 0, stream>>>(xgc, w_hh1, b_hh1,
                                                    h0 + (size_t)B * H, h1s, y1c, Sc, first);
        // 5) out = y1 @ w_out^T + b_out
        gemm_bias<<<gO, blk, 0, stream>>>(y1c, w_out, b_out, out + (long)s0 * OUT,
                                          Sc, (long)Sc * H, (long)H,
                                          (long)S * OUT, (long)OUT, OUT, H);
    }
}